// Round 8
// baseline (45.937 us; speedup 1.0000x reference)
//
#include <hip/hip_runtime.h>

#define WIN_SIZE   400
#define WIN_SHIFT  160
#define BATCH      32
#define T_LEN      480000
#define NFRAMES    2998                 // (480000-400)/160 + 1
#define WCHUNK     16                   // output rows per block
#define NWC        (WIN_SIZE / WCHUNK)  // 25
#define NBLOCKS    (BATCH * NWC)        // 800 = 8 * 100 (fully resident @4/CU)
#define PER_XCD    (NBLOCKS / 8)        // 100 = consecutive (b,wc) per XCD
#define FCHUNK     256                  // frames per macro-iter
#define NITER      12                   // ceil(2998/256)
#define TAILF      (NFRAMES - (NITER-1)*FCHUNK)   // 182
#define LBUF       4128                 // 16*256 + swizzle margin

typedef float f32x2 __attribute__((ext_vector_type(2)));

// XOR-swizzle (same involution both sides). Store-phase reads a=32L+2048s+i:
// bank = i ^ (L&31) -> 2 lanes/bank = free (m136). Staging writes: <=2-way.
__device__ __forceinline__ int swz(int a) { return a ^ ((a >> 5) & 31); }

// Block = (b, 16-row w-chunk). Reads: each 64B x-line (16 floats, w0..w0+15
// of one frame) is read EXACTLY ONCE chip-wide, coalesced float4. Writes: 16
// sequential streams/block advancing 1KB/iter -> L2 evicts full sequential
// bursts (vs 38K scattered 256B streams/XCD in the f-tiled layout).
__global__ __launch_bounds__(256) void window_frame_kernel(
    const float* __restrict__ x, const float* __restrict__ window,
    float* __restrict__ out)
{
    __shared__ float ls[2][LBUF];
    __shared__ float lw[WCHUNK];

    // XCD-aware bijective swizzle (800 = 8*100 exact)
    const int flat = blockIdx.x;
    const int lin  = (flat & 7) * PER_XCD + (flat >> 3);
    const int b    = lin / NWC;
    const int w0   = (lin % NWC) * WCHUNK;

    const int tid  = threadIdx.x;
    const int lane = tid & 63;
    const int wid  = tid >> 6;

    if (tid < WCHUNK) lw[tid] = window[w0 + tid];

    // thread t' = tid + 256p loads frame frl = t'>>2, floats w0+4(t'&3)..+3
    // (16B-aligned: w0 % 4 == 0). One float4 = quarter of one x-line.
    const float* __restrict__ xb = x + (long)b * T_LEN + w0;

    // T14 issue-early: prefetch iter 0 into registers
    float4 pf[4];
    #pragma unroll
    for (int p = 0; p < 4; ++p) {
        int t = tid + 256 * p;
        pf[p] = *(const float4*)(xb + (long)(t >> 2) * WIN_SHIFT + 4 * (t & 3));
    }

    for (int it = 0; it < NITER; ++it) {
        float* buf = ls[it & 1];
        const int f0 = it * FCHUNK;
        const int nf = (it == NITER - 1) ? TAILF : FCHUNK;

        // write-late: vmcnt waits land here, hidden under prior store phase
        #pragma unroll
        for (int p = 0; p < 4; ++p) {
            int t = tid + 256 * p;
            int frl = t >> 2;
            if (frl < nf) {
                float4 v = pf[p];
                int a = 16 * frl + 4 * (t & 3);
                buf[swz(a + 0)] = v.x;
                buf[swz(a + 1)] = v.y;
                buf[swz(a + 2)] = v.z;
                buf[swz(a + 3)] = v.w;
            }
        }
        __syncthreads();   // single barrier/iter: dbuf + in-order LDS pipe
                           // make next reuse of this buffer (it+2) safe.

        // issue next iter's prefetch; latency hides under store phase below
        if (it + 1 < NITER) {
            const int nf2 = (it + 1 == NITER - 1) ? TAILF : FCHUNK;
            const float* __restrict__ xn = xb + (long)(f0 + FCHUNK) * WIN_SHIFT;
            #pragma unroll
            for (int p = 0; p < 4; ++p) {
                int t = tid + 256 * p;
                int frl = t >> 2;
                if (frl < nf2)
                    pf[p] = *(const float4*)(xn + (long)frl * WIN_SHIFT + 4 * (t & 3));
            }
        }

        // store phase: wave owns rows i = 4*wid+c; lane owns frame pair
        // 2L+128s -> 512 B contiguous per wave-instr, 8B-aligned everywhere.
        #pragma unroll
        for (int c = 0; c < 4; ++c) {
            const int i = 4 * wid + c;
            const float wv = lw[i];
            float* __restrict__ orow =
                out + ((long)(b * WIN_SIZE + w0 + i)) * NFRAMES + f0;
            #pragma unroll
            for (int s = 0; s < 2; ++s) {
                int fl = 2 * lane + 128 * s;
                if (fl < nf) {
                    f32x2 v;
                    v.x = buf[swz(16 * fl + i)]        * wv;
                    v.y = buf[swz(16 * (fl + 1) + i)]  * wv;
                    *(f32x2*)(orow + fl) = v;
                }
            }
        }
    }
}

extern "C" void kernel_launch(void* const* d_in, const int* in_sizes, int n_in,
                              void* d_out, int out_size, void* d_ws, size_t ws_size,
                              hipStream_t stream) {
    const float* x      = (const float*)d_in[0];
    const float* window = (const float*)d_in[1];
    // d_in[2] = win_shift scalar (160) — compile-time constant here
    float* out = (float*)d_out;

    window_frame_kernel<<<NBLOCKS, 256, 0, stream>>>(x, window, out);
}

// Round 9
// 41.407 us; speedup vs baseline: 1.1094x; 1.1094x over previous
//
#include <hip/hip_runtime.h>

#define WIN_SIZE   400
#define WIN_SHIFT  160
#define BATCH      32
#define T_LEN      480000
#define NFRAMES    2998                 // (480000-400)/160 + 1
#define RCHUNK     8                    // residues per block
#define NRC        20                   // 160/8
#define NBLOCKS    (BATCH * NRC)        // 640 = 8 * 80
#define PER_XCD    (NBLOCKS / 8)        // 80 = 4 whole batches of 20
#define NG         510                  // output frames per chunk (even)
#define SF         512                  // staged frames (NG + 2 for j-shift)
#define NITER      6                    // ceil(2998/510)
#define LBUF       (SF * RCHUNK + 32)   // 4128 (swz margin)

typedef float f32x2 __attribute__((ext_vector_type(2)));

// swz involution. Store reads a = 16L + (1024s + 8j + rr): per p=L&1 the 32
// q=L>>1 values hit 32 distinct banks -> 2 lanes/bank = free (m136).
__device__ __forceinline__ int swz(int a) { return a ^ ((a >> 5) & 31); }

// Block = (b, residue chunk r0..r0+7). Rows w = r0+rr+160j (j=0,1[,2 if
// r0<80]) all decimate the SAME x stream x[b][160g + r] -> x read EXACTLY
// once chip-wide (61 MB), writes are 16-24 long sequential streams (512B/
// wave-instr, 2KB/iter/row) -> per-XCD dirty set ~< L2.
__global__ __launch_bounds__(256) void window_frame_kernel(
    const float* __restrict__ x, const float* __restrict__ window,
    float* __restrict__ out)
{
    __shared__ float ls[2][LBUF];
    __shared__ float lw[24];

    // XCD-aware bijective swizzle: each XCD owns 80 consecutive (b,rc) ids
    const int flat = blockIdx.x;
    const int lin  = (flat & 7) * PER_XCD + (flat >> 3);
    const int b    = lin / NRC;
    const int rc   = lin % NRC;
    const int r0   = rc * RCHUNK;
    const int nrows = (r0 < 80) ? 24 : 16;   // j=2 exists iff r0+320 < 400

    const int tid = threadIdx.x;
    if (tid < nrows)
        lw[tid] = window[r0 + (tid & 7) + WIN_SHIFT * (tid >> 3)];

    const float* __restrict__ xb = x + (long)b * T_LEN + r0;

    // T14 issue-early: prefetch chunk 0 (all 512 frames valid: 3000 total)
    float4 pf[4];
    #pragma unroll
    for (int p = 0; p < 4; ++p) {
        int i4 = tid + 256 * p;              // [0,1024): frame dg=i4>>1, half
        pf[p] = *(const float4*)(xb + (long)(i4 >> 1) * WIN_SHIFT + 4 * (i4 & 1));
    }

    for (int it = 0; it < NITER; ++it) {
        float* buf = ls[it & 1];
        const int g0     = it * NG;
        const int sAvail = min(SF, 3000 - g0);      // staged frames valid
        const int nf     = min(NG, NFRAMES - g0);   // output frames (even)

        // write-late: vmcnt waits land here, hidden under prior store phase
        #pragma unroll
        for (int p = 0; p < 4; ++p) {
            int i4 = tid + 256 * p;
            if ((i4 >> 1) < sAvail) {
                float4 v = pf[p];
                int a = 4 * i4;
                buf[swz(a + 0)] = v.x;
                buf[swz(a + 1)] = v.y;
                buf[swz(a + 2)] = v.z;
                buf[swz(a + 3)] = v.w;
            }
        }
        __syncthreads();   // single barrier/iter: dbuf; buf(it) overwritten
                           // only at it+2 staging, after barrier(it+1) which
                           // follows every wave's store(it).

        // issue next chunk's loads; latency hides under store phase below
        if (it + 1 < NITER) {
            const int g0n  = g0 + NG;
            const int sAv2 = min(SF, 3000 - g0n);
            const float* __restrict__ xn = xb + (long)g0n * WIN_SHIFT;
            #pragma unroll
            for (int p = 0; p < 4; ++p) {
                int i4 = tid + 256 * p;
                if ((i4 >> 1) < sAv2)
                    pf[p] = *(const float4*)(xn + (long)(i4 >> 1) * WIN_SHIFT + 4 * (i4 & 1));
            }
        }

        // store phase: wave owns rows i = wid, wid+4, ...; row (rr,j) at
        // output-frame f reads staged frame f+j. 128 floats = 512 B
        // contiguous per wave-instr, single stream per row.
        const int lane = tid & 63;
        const int wid  = tid >> 6;
        for (int i = wid; i < nrows; i += 4) {
            const int rr = i & 7, j = i >> 3;
            const int w  = r0 + rr + WIN_SHIFT * j;
            const float wv = lw[i];
            float* __restrict__ orow =
                out + ((long)(b * WIN_SIZE + w)) * NFRAMES + g0;
            #pragma unroll
            for (int s = 0; s < 4; ++s) {
                int fl = 2 * lane + 128 * s;
                if (fl < nf) {
                    f32x2 v;
                    v.x = buf[swz(8 * (fl + j)     + rr)] * wv;
                    v.y = buf[swz(8 * (fl + 1 + j) + rr)] * wv;
                    *(f32x2*)(orow + fl) = v;   // 8B-aligned: row start & g0 even
                }
            }
        }
    }
}

extern "C" void kernel_launch(void* const* d_in, const int* in_sizes, int n_in,
                              void* d_out, int out_size, void* d_ws, size_t ws_size,
                              hipStream_t stream) {
    const float* x      = (const float*)d_in[0];
    const float* window = (const float*)d_in[1];
    // d_in[2] = win_shift scalar (160) — compile-time constant here
    float* out = (float*)d_out;

    window_frame_kernel<<<NBLOCKS, 256, 0, stream>>>(x, window, out);
}

// Round 10
// 39.177 us; speedup vs baseline: 1.1726x; 1.0569x over previous
//
#include <hip/hip_runtime.h>

#define WIN_SIZE   400
#define WIN_SHIFT  160
#define BATCH      32
#define T_LEN      480000
#define NFRAMES    2998                  // (480000-400)/160 + 1
#define FTILE      64
#define NTILES     47                    // ceil(2998/64)
#define NBLOCKS    (NTILES * BATCH)      // 1504 = 8 * 188
#define PER_XCD    (NBLOCKS / 8)         // 188 = 4 whole batches of 47 tiles
#define SAMPLES    ((FTILE-1)*WIN_SHIFT + WIN_SIZE)   // 10480
#define SAMPLES_PAD 10496

typedef float f32x2 __attribute__((ext_vector_type(2)));
// 16B store at 8B alignment (odd output rows): AMDGPU emits
// global_store_dwordx4 for align>=4, so keep alignment promise at 8.
struct __align__(8) F4 { f32x2 lo, hi; };

// XOR-swizzle. Store-phase reads a = 640*k2b + 160*j + w:
//   bank = (w&31) ^ ((20*k2b + 5j + w>>5)&31); rsel gives exact low-2 bits
//   of the left term, 20*k2b mod 32 spans 8 even residues x2 ->
//   32 distinct banks x 2 lanes = free (m136). Staging writes: <=2-way.
__device__ __forceinline__ int swz(int a) { return a ^ ((a >> 5) & 31); }

__global__ __launch_bounds__(256) void window_frame_kernel(
    const float* __restrict__ x, const float* __restrict__ window,
    float* __restrict__ out)
{
    __shared__ float lx[SAMPLES_PAD];
    __shared__ float lw[WIN_SIZE];

    // XCD-aware bijective swizzle: each XCD owns 188 consecutive (b,tile) ids
    // = 4 whole batches -> neighbor tiles share an L2.
    const int flat = blockIdx.x;
    const int lin  = (flat & 7) * PER_XCD + (flat >> 3);
    const int b    = lin / NTILES;
    const int k    = lin % NTILES;

    const long base  = (long)b * T_LEN + (long)k * FTILE * WIN_SHIFT;
    const int  avail = T_LEN - k * FTILE * WIN_SHIFT;    // multiple of 16
    const int  need  = min(SAMPLES, avail);
    const int  need4 = need >> 2;

    const int tid = threadIdx.x;

    for (int i = tid; i < WIN_SIZE; i += 256) lw[i] = window[i];

    // stage x: coalesced float4 loads -> swizzled scalar LDS writes
    const float4* __restrict__ xg = (const float4*)(x + base);
    for (int i4 = tid; i4 < need4; i4 += 256) {
        float4 v = xg[i4];
        int a = i4 << 2;
        lx[swz(a + 0)] = v.x;
        lx[swz(a + 1)] = v.y;
        lx[swz(a + 2)] = v.z;
        lx[swz(a + 3)] = v.w;
    }
    __syncthreads();

    const int lane = tid & 63;
    const int wid  = tid >> 6;
    const int k2b  = lane & 15;          // frame-quad: frames 4k2b..4k2b+3
    const int rsel = lane >> 4;          // row within wave's 4-row group
    const int fr   = FTILE * k + 4 * k2b;
    const int rem  = NFRAMES - fr;       // >=4 except tail tile k2b=13 (rem=2)
    const int a0   = 640 * k2b;

    // wave covers rows {4wid..4wid+3} x 64 frames per pass; 25 passes.
    // store: 4 contiguous 256 B segments per wave-instr (dwordx4 lanes).
    #pragma unroll 5
    for (int p = 0; p < 25; ++p) {
        const int w = 4 * wid + rsel + 16 * p;
        const float lwv = lw[w];
        f32x2 v01, v23;
        v01.x = lx[swz(a0 +       w)] * lwv;
        v01.y = lx[swz(a0 + 160 + w)] * lwv;
        v23.x = lx[swz(a0 + 320 + w)] * lwv;
        v23.y = lx[swz(a0 + 480 + w)] * lwv;
        float* op = out + ((long)b * WIN_SIZE + w) * NFRAMES + fr;
        if (rem >= 4) {
            F4 s; s.lo = v01; s.hi = v23;
            *(F4*)op = s;
        } else if (rem == 2) {
            *(f32x2*)op = v01;           // tail tile, frames 2996-2997
        }
    }
}

extern "C" void kernel_launch(void* const* d_in, const int* in_sizes, int n_in,
                              void* d_out, int out_size, void* d_ws, size_t ws_size,
                              hipStream_t stream) {
    const float* x      = (const float*)d_in[0];
    const float* window = (const float*)d_in[1];
    // d_in[2] = win_shift scalar (160) — compile-time constant here
    float* out = (float*)d_out;

    window_frame_kernel<<<NBLOCKS, 256, 0, stream>>>(x, window, out);
}